// Round 5
// baseline (1632.033 us; speedup 1.0000x reference)
//
#include <hip/hip_runtime.h>
#include <cstdint>
#include <cstddef>

#define TSTEPS 1024
#define NB 256
#define NI 128
#define NH 128
#define NC 18
#define CH 32
#define NCHUNK (TSTEPS/CH)   // 32
#define XGP 514              // xg row pad (bank-conflict-free f16 stores)

typedef _Float16 f16x8 __attribute__((ext_vector_type(8)));
typedef float    f32x4 __attribute__((ext_vector_type(4)));
typedef _Float16 half2_t __attribute__((ext_vector_type(2)));

__device__ __forceinline__ half2_t as_h2(uint32_t v){
  union { uint32_t u; half2_t h; } cv; cv.u = v; return cv.h;
}
__device__ __forceinline__ uint32_t pku(float a, float b){
  union { half2_t h; uint32_t u; } cv; cv.h.x=(_Float16)a; cv.h.y=(_Float16)b; return cv.u;
}
__device__ __forceinline__ float dot2f(half2_t a, half2_t b, float c){
#if __has_builtin(__builtin_amdgcn_fdot2)
  return __builtin_amdgcn_fdot2(a, b, c, false);
#else
  return c + (float)a.x*(float)b.x + (float)a.y*(float)b.y;
#endif
}
__device__ __forceinline__ float fast_rcp(float x){
#if __has_builtin(__builtin_amdgcn_rcpf)
  return __builtin_amdgcn_rcpf(x);
#else
  return 1.f / x;
#endif
}
__device__ __forceinline__ float sigm(float v){
  v = fminf(fmaxf(v, -30.f), 30.f);
  return fast_rcp(1.f + __expf(-v));
}
__device__ __forceinline__ float tanhx(float v){
  v = fminf(fmaxf(v, -15.f), 15.f);
  float e = __expf(2.f*v);
  return (e - 1.f) * fast_rcp(e + 1.f);
}
__device__ __forceinline__ f16x8 ldrow_f16(const float* base){
  float4 f0 = ((const float4*)base)[0];
  float4 f1 = ((const float4*)base)[1];
  f16x8 r;
  r[0]=(_Float16)f0.x; r[1]=(_Float16)f0.y; r[2]=(_Float16)f0.z; r[3]=(_Float16)f0.w;
  r[4]=(_Float16)f1.x; r[5]=(_Float16)f1.y; r[6]=(_Float16)f1.z; r[7]=(_Float16)f1.w;
  return r;
}

// 128 blocks; block handles batch rows 2b, 2b+1 braided at half-step skew.
// half1: MFMA row A (step t) || activation row B (step t-1).  barrier.
// half2: MFMA row B (step t) || activation row A (step t).    barrier.
// MFMA results drain across the barrier (register results, not memory),
// so each half's serial act chain hides under the other row's MFMA issue.
__global__ __launch_bounds__(512, 2) void lstm_braid(
    const float* __restrict__ x,      // [T,B,I]
    const float* __restrict__ h0,     // [B,H]
    const float* __restrict__ c0,     // [B,H]
    const float* __restrict__ Wih,    // [4H,I]
    const float* __restrict__ Whh,    // [4H,H]
    const float* __restrict__ bih,    // [4H]
    const float* __restrict__ bhh,    // [4H]
    const float* __restrict__ fcW,    // [18,H]
    const float* __restrict__ fcb,    // [18]
    float* __restrict__ out,          // [T,B,18]
    float* __restrict__ hT,           // [B,H]
    float* __restrict__ cT)           // [B,H]
{
  const int b0   = 2*blockIdx.x;
  const int b1   = b0 + 1;
  const int tid  = threadIdx.x;
  const int w    = tid >> 6;      // wave 0..7
  const int l    = tid & 63;
  const int n    = l & 15;
  const int quad = l >> 4;

  __shared__ __align__(16) _Float16 xs[2][CH][136];   // x chunk f16      17408 B
  __shared__ __align__(16) _Float16 xg[2][CH][XGP];   // x-gates f16      65792 B
  __shared__ __align__(16) _Float16 hbuf[2][2][128];  // [row][buf]         1024 B
  __shared__ __align__(16) _Float16 hist[2][CH][128]; // h history        16384 B
  __shared__ __align__(16) uint32_t fcw[NC][66];      // head W            4752 B

  // ---- persistent Whh B-frags [q][kt] (shared by both rows): 64 VGPRs ----
  f16x8 whh[4][4];
#pragma unroll
  for (int q = 0; q < 4; ++q){
    const int row = q*128 + w*16 + n;
#pragma unroll
    for (int kt = 0; kt < 4; ++kt)
      whh[q][kt] = ldrow_f16(Whh + (size_t)row*NH + kt*32 + quad*8);
  }
  float biasq[4];
#pragma unroll
  for (int q = 0; q < 4; ++q){
    const int g = q*128 + w*16 + n;
    biasq[q] = bih[g] + bhh[g];
  }
  float cstA = c0[(size_t)b0*NH + w*16 + n];   // valid lanes l<16
  float cstB = c0[(size_t)b1*NH + w*16 + n];

  if (tid < 128){
    hbuf[0][0][tid] = (_Float16)h0[(size_t)b0*NH + tid];
    hbuf[1][0][tid] = (_Float16)h0[(size_t)b1*NH + tid];
  }
#pragma unroll
  for (int r = 0; r < 3; ++r){
    int idx = tid + 512*r;
    if (idx < NC*64){
      int j = idx >> 6, k = idx & 63;
      float2 f = ((const float2*)(fcW + (size_t)j*NH))[k];
      fcw[j][k] = pku(f.x, f.y);
    }
  }
  __syncthreads();

  int pA = 0, pB = 0;
  float gA[4], gB[4];
  f16x8 afrA[4] = { (f16x8)(_Float16)0, (f16x8)(_Float16)0,
                    (f16x8)(_Float16)0, (f16x8)(_Float16)0 };
  f16x8 afrB[4] = { (f16x8)(_Float16)0, (f16x8)(_Float16)0,
                    (f16x8)(_Float16)0, (f16x8)(_Float16)0 };

  auto act_B = [&](int hist_ts){
    if (l < 16){
      float iv = sigm(gB[0]);
      float fv = sigm(gB[1]);
      float gv = tanhx(gB[2]);
      float ov = sigm(gB[3]);
      cstB = fv*cstB + iv*gv;
      float hval = ov * tanhx(cstB);
      _Float16 hh = (_Float16)hval;
      hbuf[1][pB^1][w*16 + l] = hh;
      hist[1][hist_ts][w*16 + l] = hh;
    }
    pB ^= 1;
  };

  auto head = [&](int tbase){
    const int rsb = tid >> 4;            // 0..31
    const int jb  = tid & 15;
#pragma unroll
    for (int h2i = 0; h2i < 2; ++h2i){
      const int rs2 = rsb + 32*h2i;      // 0..63
      const int rowsel = rs2 >> 5, step = rs2 & 31;
      const uint4* hb = (const uint4*)&hist[rowsel][step][0];
#pragma unroll
      for (int jj = 0; jj < 2; ++jj){
        const int j = jj*16 + jb;
        if (j < NC){
          const uint2* fw = (const uint2*)&fcw[j][0];
          float a0=0.f, a1=0.f, a2=0.f, a3=0.f;
#pragma unroll
          for (int q = 0; q < 4; ++q){
            uint4 v0 = hb[q], v1 = hb[4+q], v2 = hb[8+q], v3 = hb[12+q];
            uint2 f0 = fw[2*q],    f0b = fw[2*q+1];
            uint2 f1 = fw[8+2*q],  f1b = fw[8+2*q+1];
            uint2 f2 = fw[16+2*q], f2b = fw[16+2*q+1];
            uint2 f3 = fw[24+2*q], f3b = fw[24+2*q+1];
            a0 = dot2f(as_h2(f0.x),  as_h2(v0.x), a0);
            a1 = dot2f(as_h2(f1.x),  as_h2(v1.x), a1);
            a2 = dot2f(as_h2(f2.x),  as_h2(v2.x), a2);
            a3 = dot2f(as_h2(f3.x),  as_h2(v3.x), a3);
            a0 = dot2f(as_h2(f0.y),  as_h2(v0.y), a0);
            a1 = dot2f(as_h2(f1.y),  as_h2(v1.y), a1);
            a2 = dot2f(as_h2(f2.y),  as_h2(v2.y), a2);
            a3 = dot2f(as_h2(f3.y),  as_h2(v3.y), a3);
            a0 = dot2f(as_h2(f0b.x), as_h2(v0.z), a0);
            a1 = dot2f(as_h2(f1b.x), as_h2(v1.z), a1);
            a2 = dot2f(as_h2(f2b.x), as_h2(v2.z), a2);
            a3 = dot2f(as_h2(f3b.x), as_h2(v3.z), a3);
            a0 = dot2f(as_h2(f0b.y), as_h2(v0.w), a0);
            a1 = dot2f(as_h2(f1b.y), as_h2(v1.w), a1);
            a2 = dot2f(as_h2(f2b.y), as_h2(v2.w), a2);
            a3 = dot2f(as_h2(f3b.y), as_h2(v3.w), a3);
          }
          out[(size_t)(tbase+step)*NB*NC + (size_t)(b0+rowsel)*NC + j] =
              (a0+a1) + (a2+a3) + fcb[j];
        }
      }
    }
  };

  for (int t = 0; t < TSTEPS; ++t){
    const int ts = t & (CH-1);

    if (ts == 0){
      // ---- chunk boundary: actB(t-1), publish, stage+head, xGEMM ----
      if (t > 0) act_B(CH-1);
      __syncthreads();
#pragma unroll
      for (int u = 0; u < 4; ++u){
        int idx = tid + 512*u;               // 2048 float4
        int rowsel = idx >> 10;
        int rem = idx & 1023;
        int st = rem >> 5, k4 = rem & 31;
        float4 f = ((const float4*)(x + ((size_t)(t+st)*NB + (b0+rowsel))*NI))[k4];
        union { _Float16 h[4]; uint2 u2; } pk4;
        pk4.h[0]=(_Float16)f.x; pk4.h[1]=(_Float16)f.y;
        pk4.h[2]=(_Float16)f.z; pk4.h[3]=(_Float16)f.w;
        *(uint2*)&xs[rowsel][st][4*k4] = pk4.u2;
      }
      if (t > 0) head(t - CH);               // overlaps staging latency
      __syncthreads();
      {
        int lofs = 0;
        asm volatile("" : "+v"(lofs));       // reload Wih per chunk (no LICM)
#pragma unroll
        for (int q = 0; q < 4; ++q){
          const int row = q*128 + w*16 + n;
          f16x8 wb[4];
#pragma unroll
          for (int kt = 0; kt < 4; ++kt)
            wb[kt] = ldrow_f16(Wih + (size_t)row*NI + kt*32 + quad*8 + lofs);
#pragma unroll
          for (int mt = 0; mt < 4; ++mt){
            const int rowsel = mt >> 1;
            const int sbase  = (mt & 1)*16;
            f16x8 xa[4];
#pragma unroll
            for (int kt = 0; kt < 4; ++kt)
              xa[kt] = *(const f16x8*)&xs[rowsel][sbase + n][kt*32 + quad*8];
            f32x4 acc = { biasq[q], biasq[q], biasq[q], biasq[q] };
#pragma unroll
            for (int kt = 0; kt < 4; ++kt)
              acc = __builtin_amdgcn_mfma_f32_16x16x32_f16(xa[kt], wb[kt], acc, 0, 0, 0);
#pragma unroll
            for (int r = 0; r < 4; ++r)
              xg[rowsel][sbase + quad*4 + r][w*64 + q*16 + n] = (_Float16)acc[r];
          }
        }
      }
      __syncthreads();
    }

    // ================ half1: MFMA_A(t) || actB(t-1) ================
    {
      if (n == 0){
#pragma unroll
        for (int kt = 0; kt < 4; ++kt)
          afrA[kt] = *(const f16x8*)&hbuf[0][pA][kt*32 + quad*8];
      }
      float sg[4];
#pragma unroll
      for (int q = 0; q < 4; ++q) sg[q] = (float)xg[0][ts][w*64 + q*16 + n];
      f32x4 u0[4], u1[4];
#pragma unroll
      for (int q = 0; q < 4; ++q){
        f32x4 a = { sg[q], sg[q], sg[q], sg[q] };
        a = __builtin_amdgcn_mfma_f32_16x16x32_f16(afrA[0], whh[q][0], a, 0, 0, 0);
        a = __builtin_amdgcn_mfma_f32_16x16x32_f16(afrA[1], whh[q][1], a, 0, 0, 0);
        f32x4 c = { 0.f, 0.f, 0.f, 0.f };
        c = __builtin_amdgcn_mfma_f32_16x16x32_f16(afrA[2], whh[q][2], c, 0, 0, 0);
        c = __builtin_amdgcn_mfma_f32_16x16x32_f16(afrA[3], whh[q][3], c, 0, 0, 0);
        u0[q] = a; u1[q] = c;
      }
      if (ts != 0 && t > 0) act_B(ts - 1);   // overlaps MFMA_A drain
#pragma unroll
      for (int q = 0; q < 4; ++q) gA[q] = u0[q][0] + u1[q][0];
    }
    __syncthreads();

    // ================ half2: MFMA_B(t) || actA(t) ================
    {
      if (n == 0){
#pragma unroll
        for (int kt = 0; kt < 4; ++kt)
          afrB[kt] = *(const f16x8*)&hbuf[1][pB][kt*32 + quad*8];
      }
      float sg[4];
#pragma unroll
      for (int q = 0; q < 4; ++q) sg[q] = (float)xg[1][ts][w*64 + q*16 + n];
      f32x4 u0[4], u1[4];
#pragma unroll
      for (int q = 0; q < 4; ++q){
        f32x4 a = { sg[q], sg[q], sg[q], sg[q] };
        a = __builtin_amdgcn_mfma_f32_16x16x32_f16(afrB[0], whh[q][0], a, 0, 0, 0);
        a = __builtin_amdgcn_mfma_f32_16x16x32_f16(afrB[1], whh[q][1], a, 0, 0, 0);
        f32x4 c = { 0.f, 0.f, 0.f, 0.f };
        c = __builtin_amdgcn_mfma_f32_16x16x32_f16(afrB[2], whh[q][2], c, 0, 0, 0);
        c = __builtin_amdgcn_mfma_f32_16x16x32_f16(afrB[3], whh[q][3], c, 0, 0, 0);
        u0[q] = a; u1[q] = c;
      }
      // actA(t)
      if (l < 16){
        float iv = sigm(gA[0]);
        float fv = sigm(gA[1]);
        float gv = tanhx(gA[2]);
        float ov = sigm(gA[3]);
        cstA = fv*cstA + iv*gv;
        float hval = ov * tanhx(cstA);
        _Float16 hh = (_Float16)hval;
        hbuf[0][pA^1][w*16 + l] = hh;
        hist[0][ts][w*16 + l] = hh;
        if (t == TSTEPS-1){
          hT[(size_t)b0*NH + w*16 + l] = hval;
          cT[(size_t)b0*NH + w*16 + l] = cstA;
        }
      }
      pA ^= 1;
#pragma unroll
      for (int q = 0; q < 4; ++q) gB[q] = u0[q][0] + u1[q][0];
    }
    __syncthreads();
  }

  // ---- epilogue: actB(T-1) + final head chunk + hT/cT row B ----
  if (l < 16){
    float iv = sigm(gB[0]);
    float fv = sigm(gB[1]);
    float gv = tanhx(gB[2]);
    float ov = sigm(gB[3]);
    cstB = fv*cstB + iv*gv;
    float hval = ov * tanhx(cstB);
    hist[1][CH-1][w*16 + l] = (_Float16)hval;
    hT[(size_t)b1*NH + w*16 + l] = hval;
    cT[(size_t)b1*NH + w*16 + l] = cstB;
  }
  __syncthreads();
  head(TSTEPS - CH);
}

extern "C" void kernel_launch(void* const* d_in, const int* in_sizes, int n_in,
                              void* d_out, int out_size, void* d_ws, size_t ws_size,
                              hipStream_t stream) {
  (void)in_sizes; (void)n_in; (void)d_ws; (void)ws_size; (void)out_size;
  const float* x   = (const float*)d_in[0];
  const float* h0  = (const float*)d_in[1];
  const float* c0  = (const float*)d_in[2];
  const float* Wih = (const float*)d_in[3];
  const float* Whh = (const float*)d_in[4];
  const float* bih = (const float*)d_in[5];
  const float* bhh = (const float*)d_in[6];
  const float* fcW = (const float*)d_in[7];
  const float* fcb = (const float*)d_in[8];
  float* out = (float*)d_out;
  float* hT  = out + (size_t)TSTEPS*NB*NC;   // 4,718,592
  float* cT  = hT + (size_t)NB*NH;           // +32,768
  hipLaunchKernelGGL(lstm_braid, dim3(NB/2), dim3(512), 0, stream,
                     x, h0, c0, Wih, Whh, bih, bhh, fcW, fcb, out, hT, cT);
}